// Round 8
// baseline (157.624 us; speedup 1.0000x reference)
//
#include <hip/hip_runtime.h>
#include <hip/hip_bf16.h>

namespace {
constexpr int NODES = 100000;
constexpr int EMBD  = 128;
constexpr int BATCH = 1024;
constexpr int STRIP = 160;    // 640 B/row per block; 100000/160 = 625 blocks
constexpr int NI    = 10;     // 16-col MFMA tiles per strip
constexpr int NPASS = 8;      // 1024 rows / (4 waves * 32 rows)
constexpr int NBLK  = NODES / STRIP;   // 625
constexpr int NXCD  = 8;
}

typedef __attribute__((ext_vector_type(8))) short bf16x8_t;
typedef __attribute__((ext_vector_type(4))) float f32x4_t;

__device__ __forceinline__ short f2bf(float f) {
    __hip_bfloat16 h = __float2bfloat16(f);
    short s; __builtin_memcpy(&s, &h, 2); return s;
}

// combined[b][k] = emb[subj[b]][k] * rels[rel[b]][k], bf16 (A matrix, 256 KB)
__global__ void combine_kernel(const int* __restrict__ subj,
                               const int* __restrict__ rel,
                               const float* __restrict__ emb,
                               const float* __restrict__ rels,
                               short* __restrict__ out) {
    const int b = blockIdx.x;
    const int t = threadIdx.x;
    const float v = emb[(size_t)subj[b] * EMBD + t] * rels[rel[b] * EMBD + t];
    out[b * EMBD + t] = f2bf(v);
}

// C[m][n] = sum_k A[m][k]*B[n][k]
// r5 structure + (a) bijective XCD-chunked strip swizzle: each XCD owns a
// contiguous 1/8 of the N range -> concurrent blocks on one XCD write
// adjacent 640B chunks (dense DRAM pages, per-L2 writeback locality);
// (b) nontemporal C stores + B loads: keep streaming data out of L2 so the
// hot 256KB A table (read 8x/block from L2) is never evicted.
__global__ __launch_bounds__(256, 3) void distmult_kernel(
        const short* __restrict__ A,
        const float* __restrict__ B,
        float* __restrict__ C) {
    __shared__ short Bs[STRIP * EMBD];     // 40 KB

    // bijective XCD-chunk swizzle (m204 form): q=78, r=1
    {
    }
    const int bid = (int)blockIdx.x;
    const int xcd = bid % NXCD;
    const int idx = bid / NXCD;
    constexpr int q = NBLK / NXCD;          // 78
    constexpr int r = NBLK % NXCD;          // 1
    const int strip = (xcd < r ? xcd * (q + 1) : r * (q + 1) + (xcd - r) * q) + idx;
    const int n0  = strip * STRIP;
    const int tid = (int)threadIdx.x;

    // ---- stage B strip: 20480 bf16 elems, 80/thread (10 chunks of 8)
#pragma unroll
    for (int c = 0; c < 10; ++c) {
        const int e = (c * 256 + tid) * 8;
        const int rr = e >> 7;
        const int k  = e & 127;
        const float* p = B + (size_t)(n0 + rr) * EMBD + k;
        f32x4_t lo = __builtin_nontemporal_load(reinterpret_cast<const f32x4_t*>(p));
        f32x4_t hi = __builtin_nontemporal_load(reinterpret_cast<const f32x4_t*>(p + 4));
        bf16x8_t v;
#pragma unroll
        for (int j = 0; j < 4; ++j) { v[j] = f2bf(lo[j]); v[4 + j] = f2bf(hi[j]); }
        const int byteaddr = rr * 256 + ((k * 2) ^ ((rr & 7) << 4));
        *reinterpret_cast<bf16x8_t*>(reinterpret_cast<char*>(Bs) + byteaddr) = v;
    }
    __syncthreads();

    const int w  = tid >> 6;
    const int l  = tid & 63;
    const int fr = l & 15;
    const int fq = l >> 4;
    const int swz = (fr & 7) << 4;
    const char* BsBase = reinterpret_cast<const char*>(Bs) + fr * 256;

#pragma unroll
    for (int p = 0; p < NPASS; ++p) {
        const int m0 = p * 128 + w * 32;
        bf16x8_t a[2][4];
#pragma unroll
        for (int mi = 0; mi < 2; ++mi) {
            const short* qp = A + (m0 + mi * 16 + fr) * EMBD + fq * 8;
#pragma unroll
            for (int kk = 0; kk < 4; ++kk)
                a[mi][kk] = *reinterpret_cast<const bf16x8_t*>(qp + kk * 32);
        }

        f32x4_t acc[2][NI] = {};
#pragma unroll
        for (int kk = 0; kk < 4; ++kk) {
#pragma unroll
            for (int h = 0; h < 2; ++h) {
                bf16x8_t bfr[5];
#pragma unroll
                for (int j = 0; j < 5; ++j) {
                    const int ni = h * 5 + j;
                    const int byteoff = ni * 4096 + ((kk * 64 + fq * 16) ^ swz);
                    bfr[j] = *reinterpret_cast<const bf16x8_t*>(BsBase + byteoff);
                }
#pragma unroll
                for (int mi = 0; mi < 2; ++mi)
#pragma unroll
                    for (int j = 0; j < 5; ++j)
                        acc[mi][h * 5 + j] = __builtin_amdgcn_mfma_f32_16x16x32_bf16(
                            bfr[j], a[mi][kk], acc[mi][h * 5 + j], 0, 0, 0);
            }
        }

#pragma unroll
        for (int mi = 0; mi < 2; ++mi) {
            const size_t rowoff = (size_t)(m0 + mi * 16 + fr) * NODES;
#pragma unroll
            for (int ni = 0; ni < NI; ++ni)
                __builtin_nontemporal_store(
                    acc[mi][ni],
                    reinterpret_cast<f32x4_t*>(C + rowoff + n0 + ni * 16 + fq * 4));
        }
    }
}

extern "C" void kernel_launch(void* const* d_in, const int* in_sizes, int n_in,
                              void* d_out, int out_size, void* d_ws, size_t ws_size,
                              hipStream_t stream) {
    const int*   subj = (const int*)d_in[0];
    const int*   rel  = (const int*)d_in[1];
    const float* emb  = (const float*)d_in[2];
    const float* rels = (const float*)d_in[3];
    float* out = (float*)d_out;
    short* combined = (short*)d_ws;   // 256 KB

    combine_kernel<<<BATCH, EMBD, 0, stream>>>(subj, rel, emb, rels, combined);
    distmult_kernel<<<NBLK, 256, 0, stream>>>(combined, emb, out);
}

// Round 9
// 114.884 us; speedup vs baseline: 1.3720x; 1.3720x over previous
//
#include <hip/hip_runtime.h>
#include <hip/hip_bf16.h>

namespace {
constexpr int NODES = 100000;
constexpr int EMBD  = 128;
constexpr int BATCH = 1024;
constexpr int STRIP = 160;    // 640 B/row per block; 100000/160 = 625 blocks
constexpr int NI    = 10;     // 16-col MFMA tiles per strip
constexpr int NPASS = 8;      // 1024 rows / (4 waves * 32 rows)
constexpr int NBLK  = NODES / STRIP;   // 625
constexpr int NXCD  = 8;
}

typedef __attribute__((ext_vector_type(8))) short bf16x8_t;
typedef __attribute__((ext_vector_type(4))) float f32x4_t;

__device__ __forceinline__ short f2bf(float f) {
    __hip_bfloat16 h = __float2bfloat16(f);
    short s; __builtin_memcpy(&s, &h, 2); return s;
}

// combined[b][k] = emb[subj[b]][k] * rels[rel[b]][k], bf16 (A matrix, 256 KB)
__global__ void combine_kernel(const int* __restrict__ subj,
                               const int* __restrict__ rel,
                               const float* __restrict__ emb,
                               const float* __restrict__ rels,
                               short* __restrict__ out) {
    const int b = blockIdx.x;
    const int t = threadIdx.x;
    const float v = emb[(size_t)subj[b] * EMBD + t] * rels[rel[b] * EMBD + t];
    out[b * EMBD + t] = f2bf(v);
}

// C[m][n] = sum_k A[m][k]*B[n][k]
// EXACT r5 structure (112.8 us) + ONE change: bijective XCD-chunk swizzle
// (m204 form) so each XCD owns a contiguous ~78-strip span of N. Concurrent
// blocks on an XCD then write a dense ~50 KB span of every C row (DRAM page
// locality) and read a contiguous B panel into their private L2.
// Stores/loads remain normal (L2 write-allocate assembles full lines).
__global__ __launch_bounds__(256, 3) void distmult_kernel(
        const short* __restrict__ A,
        const float* __restrict__ B,
        float* __restrict__ C) {
    __shared__ short Bs[STRIP * EMBD];     // 40 KB

    const int bid = (int)blockIdx.x;
    const int xcd = bid % NXCD;
    const int idx = bid / NXCD;
    constexpr int q = NBLK / NXCD;          // 78
    constexpr int r = NBLK % NXCD;          // 1
    const int strip = (xcd < r ? xcd * (q + 1) : r * (q + 1) + (xcd - r) * q) + idx;
    const int n0  = strip * STRIP;
    const int tid = (int)threadIdx.x;

    // ---- stage B strip: 20480 bf16 elems, 80/thread (10 chunks of 8)
#pragma unroll
    for (int c = 0; c < 10; ++c) {
        const int e = (c * 256 + tid) * 8;
        const int rr = e >> 7;
        const int k  = e & 127;
        const float* p = B + (size_t)(n0 + rr) * EMBD + k;
        f32x4_t lo = *reinterpret_cast<const f32x4_t*>(p);
        f32x4_t hi = *reinterpret_cast<const f32x4_t*>(p + 4);
        bf16x8_t v;
#pragma unroll
        for (int j = 0; j < 4; ++j) { v[j] = f2bf(lo[j]); v[4 + j] = f2bf(hi[j]); }
        const int byteaddr = rr * 256 + ((k * 2) ^ ((rr & 7) << 4));
        *reinterpret_cast<bf16x8_t*>(reinterpret_cast<char*>(Bs) + byteaddr) = v;
    }
    __syncthreads();

    const int w  = tid >> 6;
    const int l  = tid & 63;
    const int fr = l & 15;
    const int fq = l >> 4;
    const int swz = (fr & 7) << 4;
    const char* BsBase = reinterpret_cast<const char*>(Bs) + fr * 256;

#pragma unroll
    for (int p = 0; p < NPASS; ++p) {
        const int m0 = p * 128 + w * 32;
        bf16x8_t a[2][4];
#pragma unroll
        for (int mi = 0; mi < 2; ++mi) {
            const short* qp = A + (m0 + mi * 16 + fr) * EMBD + fq * 8;
#pragma unroll
            for (int kk = 0; kk < 4; ++kk)
                a[mi][kk] = *reinterpret_cast<const bf16x8_t*>(qp + kk * 32);
        }

        f32x4_t acc[2][NI] = {};
#pragma unroll
        for (int kk = 0; kk < 4; ++kk) {
#pragma unroll
            for (int h = 0; h < 2; ++h) {
                bf16x8_t bfr[5];
#pragma unroll
                for (int j = 0; j < 5; ++j) {
                    const int ni = h * 5 + j;
                    const int byteoff = ni * 4096 + ((kk * 64 + fq * 16) ^ swz);
                    bfr[j] = *reinterpret_cast<const bf16x8_t*>(BsBase + byteoff);
                }
#pragma unroll
                for (int mi = 0; mi < 2; ++mi)
#pragma unroll
                    for (int j = 0; j < 5; ++j)
                        acc[mi][h * 5 + j] = __builtin_amdgcn_mfma_f32_16x16x32_bf16(
                            bfr[j], a[mi][kk], acc[mi][h * 5 + j], 0, 0, 0);
            }
        }

#pragma unroll
        for (int mi = 0; mi < 2; ++mi) {
            const size_t rowoff = (size_t)(m0 + mi * 16 + fr) * NODES;
#pragma unroll
            for (int ni = 0; ni < NI; ++ni)
                *reinterpret_cast<f32x4_t*>(C + rowoff + n0 + ni * 16 + fq * 4) =
                    acc[mi][ni];
        }
    }
}

extern "C" void kernel_launch(void* const* d_in, const int* in_sizes, int n_in,
                              void* d_out, int out_size, void* d_ws, size_t ws_size,
                              hipStream_t stream) {
    const int*   subj = (const int*)d_in[0];
    const int*   rel  = (const int*)d_in[1];
    const float* emb  = (const float*)d_in[2];
    const float* rels = (const float*)d_in[3];
    float* out = (float*)d_out;
    short* combined = (short*)d_ws;   // 256 KB

    combine_kernel<<<BATCH, EMBD, 0, stream>>>(subj, rel, emb, rels, combined);
    distmult_kernel<<<NBLK, 256, 0, stream>>>(combined, emb, out);
}